// Round 1
// baseline (189.632 us; speedup 1.0000x reference)
//
#include <hip/hip_runtime.h>
#include <cmath>

#define N_ 32
#define B_ 64
#define T_ 8192
#define NBLK1 1024             // 16 c-groups (512 t) * 64 b
#define PS 2176                // 2048 gram (pp|pn) + 128 stats

typedef _Float16 half8 __attribute__((ext_vector_type(8)));
typedef float floatx4 __attribute__((ext_vector_type(4)));

// convert 8 f32 -> f16 fragment, accumulating sum and sum-of-squares on the way
__device__ __forceinline__ half8 cvt8(const float4 v0, const float4 v1,
                                      float& s, float& s2) {
    s += v0.x + v0.y + v0.z + v0.w + v1.x + v1.y + v1.z + v1.w;
    s2 = fmaf(v0.x, v0.x, s2); s2 = fmaf(v0.y, v0.y, s2);
    s2 = fmaf(v0.z, v0.z, s2); s2 = fmaf(v0.w, v0.w, s2);
    s2 = fmaf(v1.x, v1.x, s2); s2 = fmaf(v1.y, v1.y, s2);
    s2 = fmaf(v1.z, v1.z, s2); s2 = fmaf(v1.w, v1.w, s2);
    half8 r = {(_Float16)v0.x, (_Float16)v0.y, (_Float16)v0.z, (_Float16)v0.w,
               (_Float16)v1.x, (_Float16)v1.y, (_Float16)v1.z, (_Float16)v1.w};
    return r;
}

// ---------------- Stage 1: direct global->register MFMA, no staging barriers ----
// grid 1024 = 16 cg (512 t) * 64 b; block 256 (4 waves), wave owns a 128-t slice.
// Each wave loads pos rows (m, m+16) and neg rows (m, m+16) ONCE (A-frag layout
// A[m=lane&15][k=(lane>>4)*8+j] maps straight onto contiguous 32 B per lane in
// global), converts f32->f16 in-register, and computes all pp+pn quadrants:
// zero load redundancy, 32 dwordx4 in flight per wave, no mid-loop barriers.
__global__ __launch_bounds__(256, 2)
void k_stage1(const float* __restrict__ pos, const float* __restrict__ neg,
              float* __restrict__ pt, double* __restrict__ accs,
              unsigned* __restrict__ ctr) {
    __shared__ float red_s[PS];
    const int bid = blockIdx.x;
    const int b = bid & 63, cg = bid >> 6;      // bid = cg*64 + b
    const int tid = threadIdx.x;
    const int w = tid >> 6, lane = tid & 63;
    const int m = lane & 15, h = lane >> 4;     // A-frag coords

    if (bid == 0 && tid == 0) { accs[0] = 0.0; accs[1] = 0.0; *ctr = 0u; }

    const long tb = (long)cg * 512 + w * 128 + h * 8;
    const float4* pa0 = (const float4*)(pos + ((long)m * B_ + b) * T_ + tb);
    const float4* pa1 = (const float4*)(pos + ((long)(m + 16) * B_ + b) * T_ + tb);
    const float4* pb0 = (const float4*)(neg + ((long)m * B_ + b) * T_ + tb);
    const float4* pb1 = (const float4*)(neg + ((long)(m + 16) * B_ + b) * T_ + tb);

    // issue ALL loads up front (4 k-steps * 8 dwordx4) -> deep MLP, no phases
    float4 a0[4][2], a1[4][2], b0[4][2], b1[4][2];
#pragma unroll
    for (int kk = 0; kk < 4; ++kk) {
        a0[kk][0] = pa0[kk * 8]; a0[kk][1] = pa0[kk * 8 + 1];
        a1[kk][0] = pa1[kk * 8]; a1[kk][1] = pa1[kk * 8 + 1];
        b0[kk][0] = pb0[kk * 8]; b0[kk][1] = pb0[kk * 8 + 1];
        b1[kk][0] = pb1[kk * 8]; b1[kk][1] = pb1[kk * 8 + 1];
    }

    floatx4 cPP00 = {}, cPP01 = {}, cPP11 = {};
    floatx4 cPN00 = {}, cPN01 = {}, cPN10 = {}, cPN11 = {};
    float sxl = 0.f, sxl2 = 0.f, sxh = 0.f, sxh2 = 0.f;
    float syl = 0.f, syl2 = 0.f, syh = 0.f, syh2 = 0.f;

#pragma unroll
    for (int kk = 0; kk < 4; ++kk) {
        half8 fa0 = cvt8(a0[kk][0], a0[kk][1], sxl, sxl2);
        half8 fa1 = cvt8(a1[kk][0], a1[kk][1], sxh, sxh2);
        half8 fb0 = cvt8(b0[kk][0], b0[kk][1], syl, syl2);
        half8 fb1 = cvt8(b1[kk][0], b1[kk][1], syh, syh2);
        // mfma(rowfragX, rowfragY) = X . Y^T (same convention as prior kernel)
        cPP00 = __builtin_amdgcn_mfma_f32_16x16x32_f16(fa0, fa0, cPP00, 0, 0, 0);
        cPP01 = __builtin_amdgcn_mfma_f32_16x16x32_f16(fa0, fa1, cPP01, 0, 0, 0);
        cPP11 = __builtin_amdgcn_mfma_f32_16x16x32_f16(fa1, fa1, cPP11, 0, 0, 0);
        cPN00 = __builtin_amdgcn_mfma_f32_16x16x32_f16(fa0, fb0, cPN00, 0, 0, 0);
        cPN01 = __builtin_amdgcn_mfma_f32_16x16x32_f16(fa0, fb1, cPN01, 0, 0, 0);
        cPN10 = __builtin_amdgcn_mfma_f32_16x16x32_f16(fa1, fb0, cPN10, 0, 0, 0);
        cPN11 = __builtin_amdgcn_mfma_f32_16x16x32_f16(fa1, fb1, cPN11, 0, 0, 0);
    }

    // fold the 4 h-lane slices of each row's stats (lanes m, m+16, m+32, m+48)
    sxl += __shfl_xor(sxl, 16);   sxl += __shfl_xor(sxl, 32);
    sxl2 += __shfl_xor(sxl2, 16); sxl2 += __shfl_xor(sxl2, 32);
    sxh += __shfl_xor(sxh, 16);   sxh += __shfl_xor(sxh, 32);
    sxh2 += __shfl_xor(sxh2, 16); sxh2 += __shfl_xor(sxh2, 32);
    syl += __shfl_xor(syl, 16);   syl += __shfl_xor(syl, 32);
    syl2 += __shfl_xor(syl2, 16); syl2 += __shfl_xor(syl2, 32);
    syh += __shfl_xor(syh, 16);   syh += __shfl_xor(syh, 32);
    syh2 += __shfl_xor(syh2, 16); syh2 += __shfl_xor(syh2, 32);

    // combine the block's 4 waves in LDS (deterministic sequential rounds).
    // pp quadrant (1,0) is never produced -> stays 0 (stage 2 masks it anyway).
    for (int i = tid; i < PS; i += 256) red_s[i] = 0.f;
    __syncthreads();
#pragma unroll
    for (int wv = 0; wv < 4; ++wv) {
        if (w == wv) {
            // C/D layout (m89-verified): col = lane&15, row = (lane>>4)*4 + reg
#pragma unroll
            for (int reg = 0; reg < 4; ++reg) {
                const int r = h * 4 + reg;
                red_s[r * 32 + m]                    += cPP00[reg];
                red_s[r * 32 + 16 + m]               += cPP01[reg];
                red_s[(16 + r) * 32 + 16 + m]        += cPP11[reg];
                red_s[1024 + r * 32 + m]             += cPN00[reg];
                red_s[1024 + r * 32 + 16 + m]        += cPN01[reg];
                red_s[1024 + (16 + r) * 32 + m]      += cPN10[reg];
                red_s[1024 + (16 + r) * 32 + 16 + m] += cPN11[reg];
            }
            const int row = (h & 1) * 16 + m;
            const int base = 2048 + (h >> 1) * 64;   // h<2: sx block, h>=2: sy block
            const float s1 = (h == 0) ? sxl : (h == 1) ? sxh : (h == 2) ? syl : syh;
            const float s2 = (h == 0) ? sxl2 : (h == 1) ? sxh2 : (h == 2) ? syl2 : syh2;
            red_s[base + row] += s1;
            red_s[base + 32 + row] += s2;
        }
        __syncthreads();
    }

    // transposed store: pt[o][bid] so stage 2's per-b chunk reduce is coalesced
    for (int i = tid; i < PS; i += 256)
        pt[(long)i * NBLK1 + bid] = red_s[i];
}

// ---------------- Stage 2 (fused): chunk-reduce + pearson + exp + final --------
// one wave per (mat,n,m) entry; lane = b. Reads pt[o][cg*64+b]: per-lane sum over
// the 16 cg is 16 coalesced 256B wave-loads. Block partial sums -> 2 double
// atomicAdds; the last block (counter) computes the final scalar. 2 launches total.
__global__ __launch_bounds__(256)
void k_entries(const float* __restrict__ pt, double* __restrict__ accs,
               unsigned* __restrict__ ctr, float* __restrict__ out) {
    const int tid = threadIdx.x;
    const int w = tid >> 6, lane = tid & 63;
    const int entry = blockIdx.x * 4 + w;
    const int mat = entry >> 10;        // 0 = pp, 1 = pn
    const int idx = entry & 1023;
    const int n = idx >> 5, m = idx & 31;

    auto rowsum = [&](int o) -> float {
        const float* p = pt + (long)o * NBLK1 + lane;
        float s = 0.f;
#pragma unroll
        for (int c = 0; c < 16; ++c) s += p[c * 64];
        return s;
    };

    const float g    = rowsum(mat * 1024 + idx);
    const float sxn  = rowsum(2048 + n);
    const float sx2n = rowsum(2080 + n);
    const float sym  = rowsum(mat ? 2112 + m : 2048 + m);
    const float sy2m = rowsum(mat ? 2144 + m : 2080 + m);

    double num = (double)T_ * (double)g - (double)sxn * (double)sym;
    double vx = (double)T_ * (double)sx2n - (double)sxn * (double)sxn;
    double vy = (double)T_ * (double)sy2m - (double)sym * (double)sym;
    double contrib = 1.0 - num / sqrt(vx * vy);

#pragma unroll
    for (int off = 32; off; off >>= 1) contrib += __shfl_down(contrib, off);

    __shared__ double s_pos[4], s_neg[4];
    if (lane == 0) {
        double d = contrib * (1.0 / B_);
        double term = exp(d / 0.08);
        double p = 0.0, q = 0.0;
        if (mat == 0) { if (n < m) p = term; }   // strict upper triangle
        else q = term;
        s_pos[w] = p; s_neg[w] = q;
    }
    __syncthreads();
    if (tid == 0) {
        atomicAdd(&accs[0], s_pos[0] + s_pos[1] + s_pos[2] + s_pos[3]);
        atomicAdd(&accs[1], s_neg[0] + s_neg[1] + s_neg[2] + s_neg[3]);
        __threadfence();
        const unsigned old = atomicAdd(ctr, 1u);
        if (old == gridDim.x - 1) {              // last block finalizes
            __threadfence();
            const double p = ((volatile double*)accs)[0];
            const double q = ((volatile double*)accs)[1];
            out[0] = (float)log10(p / q + 1.0);
        }
    }
}

extern "C" void kernel_launch(void* const* d_in, const int* in_sizes, int n_in,
                              void* d_out, int out_size, void* d_ws, size_t ws_size,
                              hipStream_t stream) {
    (void)in_sizes; (void)n_in; (void)out_size; (void)ws_size;
    const float* pos = (const float*)d_in[0];
    const float* neg = (const float*)d_in[1];
    float* out = (float*)d_out;

    char* ws = (char*)d_ws;
    float* pt = (float*)ws;                                   // 2176*1024*4 = 8,912,896 B
    double* accs = (double*)(ws + (size_t)PS * NBLK1 * 4);    // 16 B (8-aligned)
    unsigned* ctr = (unsigned*)(ws + (size_t)PS * NBLK1 * 4 + 16);

    k_stage1<<<NBLK1, 256, 0, stream>>>(pos, neg, pt, accs, ctr);
    k_entries<<<512, 256, 0, stream>>>(pt, accs, ctr, out);
}

// Round 3
// 178.050 us; speedup vs baseline: 1.0650x; 1.0650x over previous
//
#include <hip/hip_runtime.h>
#include <cmath>

#define N_ 32
#define B_ 64
#define T_ 8192
#define NBLK1 1024             // 16 c-groups (512 t) * 64 b ; bid = cg*64 + b
#define PS 2176                // 2048 gram (pp|pn) + 128 stats

typedef _Float16 half8 __attribute__((ext_vector_type(8)));
typedef float floatx4 __attribute__((ext_vector_type(4)));

// convert 8 f32 -> f16 fragment, accumulating sum and sum-of-squares on the way
__device__ __forceinline__ half8 cvt8(const float4 v0, const float4 v1,
                                      float& s, float& s2) {
    s += v0.x + v0.y + v0.z + v0.w + v1.x + v1.y + v1.z + v1.w;
    s2 = fmaf(v0.x, v0.x, s2); s2 = fmaf(v0.y, v0.y, s2);
    s2 = fmaf(v0.z, v0.z, s2); s2 = fmaf(v0.w, v0.w, s2);
    s2 = fmaf(v1.x, v1.x, s2); s2 = fmaf(v1.y, v1.y, s2);
    s2 = fmaf(v1.z, v1.z, s2); s2 = fmaf(v1.w, v1.w, s2);
    half8 r = {(_Float16)v0.x, (_Float16)v0.y, (_Float16)v0.z, (_Float16)v0.w,
               (_Float16)v1.x, (_Float16)v1.y, (_Float16)v1.z, (_Float16)v1.w};
    return r;
}

// ---------------- Stage 1: direct global->register MFMA, no staging barriers ----
// grid 1024 = 16 cg (512 t) * 64 b; block 256 (4 waves), wave owns a 128-t slice.
// Identical compute core to round 1 (47->72us regression was NOT here). The fix:
// partial is stored CONTIGUOUS per block (float4, coalesced) instead of the 4KB-
// stride transposed scatter that turned 8.9MB of writes into ~90MB of RMW lines.
__global__ __launch_bounds__(256, 2)
void k_stage1(const float* __restrict__ pos, const float* __restrict__ neg,
              float* __restrict__ partial, double* __restrict__ accs,
              unsigned* __restrict__ ctr) {
    __shared__ __align__(16) float red_s[PS];
    const int bid = blockIdx.x;
    const int b = bid & 63, cg = bid >> 6;      // bid = cg*64 + b
    const int tid = threadIdx.x;
    const int w = tid >> 6, lane = tid & 63;
    const int m = lane & 15, h = lane >> 4;     // A-frag coords

    if (bid == 0 && tid == 0) { accs[0] = 0.0; accs[1] = 0.0; *ctr = 0u; }

    const long tb = (long)cg * 512 + w * 128 + h * 8;
    const float4* pa0 = (const float4*)(pos + ((long)m * B_ + b) * T_ + tb);
    const float4* pa1 = (const float4*)(pos + ((long)(m + 16) * B_ + b) * T_ + tb);
    const float4* pb0 = (const float4*)(neg + ((long)m * B_ + b) * T_ + tb);
    const float4* pb1 = (const float4*)(neg + ((long)(m + 16) * B_ + b) * T_ + tb);

    // issue ALL loads up front (4 k-steps * 8 dwordx4) -> deep MLP, no phases
    float4 a0[4][2], a1[4][2], b0[4][2], b1[4][2];
#pragma unroll
    for (int kk = 0; kk < 4; ++kk) {
        a0[kk][0] = pa0[kk * 8]; a0[kk][1] = pa0[kk * 8 + 1];
        a1[kk][0] = pa1[kk * 8]; a1[kk][1] = pa1[kk * 8 + 1];
        b0[kk][0] = pb0[kk * 8]; b0[kk][1] = pb0[kk * 8 + 1];
        b1[kk][0] = pb1[kk * 8]; b1[kk][1] = pb1[kk * 8 + 1];
    }

    floatx4 cPP00 = {}, cPP01 = {}, cPP11 = {};
    floatx4 cPN00 = {}, cPN01 = {}, cPN10 = {}, cPN11 = {};
    float sxl = 0.f, sxl2 = 0.f, sxh = 0.f, sxh2 = 0.f;
    float syl = 0.f, syl2 = 0.f, syh = 0.f, syh2 = 0.f;

#pragma unroll
    for (int kk = 0; kk < 4; ++kk) {
        half8 fa0 = cvt8(a0[kk][0], a0[kk][1], sxl, sxl2);
        half8 fa1 = cvt8(a1[kk][0], a1[kk][1], sxh, sxh2);
        half8 fb0 = cvt8(b0[kk][0], b0[kk][1], syl, syl2);
        half8 fb1 = cvt8(b1[kk][0], b1[kk][1], syh, syh2);
        // mfma(rowfragX, rowfragY) = X . Y^T
        cPP00 = __builtin_amdgcn_mfma_f32_16x16x32_f16(fa0, fa0, cPP00, 0, 0, 0);
        cPP01 = __builtin_amdgcn_mfma_f32_16x16x32_f16(fa0, fa1, cPP01, 0, 0, 0);
        cPP11 = __builtin_amdgcn_mfma_f32_16x16x32_f16(fa1, fa1, cPP11, 0, 0, 0);
        cPN00 = __builtin_amdgcn_mfma_f32_16x16x32_f16(fa0, fb0, cPN00, 0, 0, 0);
        cPN01 = __builtin_amdgcn_mfma_f32_16x16x32_f16(fa0, fb1, cPN01, 0, 0, 0);
        cPN10 = __builtin_amdgcn_mfma_f32_16x16x32_f16(fa1, fb0, cPN10, 0, 0, 0);
        cPN11 = __builtin_amdgcn_mfma_f32_16x16x32_f16(fa1, fb1, cPN11, 0, 0, 0);
    }

    // fold the 4 h-lane slices of each row's stats (lanes m, m+16, m+32, m+48)
    sxl += __shfl_xor(sxl, 16);   sxl += __shfl_xor(sxl, 32);
    sxl2 += __shfl_xor(sxl2, 16); sxl2 += __shfl_xor(sxl2, 32);
    sxh += __shfl_xor(sxh, 16);   sxh += __shfl_xor(sxh, 32);
    sxh2 += __shfl_xor(sxh2, 16); sxh2 += __shfl_xor(sxh2, 32);
    syl += __shfl_xor(syl, 16);   syl += __shfl_xor(syl, 32);
    syl2 += __shfl_xor(syl2, 16); syl2 += __shfl_xor(syl2, 32);
    syh += __shfl_xor(syh, 16);   syh += __shfl_xor(syh, 32);
    syh2 += __shfl_xor(syh2, 16); syh2 += __shfl_xor(syh2, 32);

    // combine the block's 4 waves in LDS (deterministic sequential rounds).
    // pp quadrant (1,0) is never produced -> stays 0 (stage 3 masks it anyway).
    for (int i = tid; i < PS; i += 256) red_s[i] = 0.f;
    __syncthreads();
#pragma unroll
    for (int wv = 0; wv < 4; ++wv) {
        if (w == wv) {
            // C/D layout (m89-verified): col = lane&15, row = (lane>>4)*4 + reg
#pragma unroll
            for (int reg = 0; reg < 4; ++reg) {
                const int r = h * 4 + reg;
                red_s[r * 32 + m]                    += cPP00[reg];
                red_s[r * 32 + 16 + m]               += cPP01[reg];
                red_s[(16 + r) * 32 + 16 + m]        += cPP11[reg];
                red_s[1024 + r * 32 + m]             += cPN00[reg];
                red_s[1024 + r * 32 + 16 + m]        += cPN01[reg];
                red_s[1024 + (16 + r) * 32 + m]      += cPN10[reg];
                red_s[1024 + (16 + r) * 32 + 16 + m] += cPN11[reg];
            }
            const int row = (h & 1) * 16 + m;
            const int base = 2048 + (h >> 1) * 64;   // h<2: sx block, h>=2: sy block
            const float s1 = (h == 0) ? sxl : (h == 1) ? sxh : (h == 2) ? syl : syh;
            const float s2 = (h == 0) ? sxl2 : (h == 1) ? sxh2 : (h == 2) ? syl2 : syh2;
            red_s[base + row] += s1;
            red_s[base + 32 + row] += s2;
        }
        __syncthreads();
    }

    // CONTIGUOUS coalesced store: partial[bid][o], float4 (8704 B per block)
    const float4* rs = (const float4*)red_s;
    float4* op = (float4*)(partial + (long)bid * PS);
    for (int i = tid; i < PS / 4; i += 256) op[i] = rs[i];
}

// ---------------- Stage 2: reduce 16 chunk partials -> per-b stats (coalesced) ----
// grid (17, 64), block 128: one thread per output element; reads are coalesced
// (consecutive threads -> consecutive o), writes red[b][o] contiguous.
__global__ void k_reduce(const float* __restrict__ partial, float* __restrict__ red) {
    const int b = blockIdx.y;
    const int o = blockIdx.x * 128 + threadIdx.x;   // 0..2175
    float s = 0.f;
#pragma unroll
    for (int c = 0; c < 16; ++c) s += partial[(long)(c * 64 + b) * PS + o];
    red[(long)b * PS + o] = s;
}

// ---------------- Stage 3 (fused): pearson + exp + block sums + final ----------
// one wave per (mat,n,m) entry; lane = b. 5 strided loads per wave from the
// 557KB L2-resident red. Block partials -> 2 double atomicAdds; last block
// (counter) computes the final scalar. 3 launches total.
__global__ __launch_bounds__(256)
void k_entries(const float* __restrict__ red, double* __restrict__ accs,
               unsigned* __restrict__ ctr, float* __restrict__ out) {
    const int tid = threadIdx.x;
    const int w = tid >> 6, lane = tid & 63;
    const int entry = blockIdx.x * 4 + w;
    const int mat = entry >> 10;        // 0 = pp, 1 = pn
    const int idx = entry & 1023;
    const int n = idx >> 5, m = idx & 31;

    const float* rb = red + (long)lane * PS;
    const float g    = rb[mat * 1024 + idx];
    const float sxn  = rb[2048 + n];
    const float sx2n = rb[2080 + n];
    const float sym  = rb[mat ? 2112 + m : 2048 + m];
    const float sy2m = rb[mat ? 2144 + m : 2080 + m];

    double num = (double)T_ * (double)g - (double)sxn * (double)sym;
    double vx = (double)T_ * (double)sx2n - (double)sxn * (double)sxn;
    double vy = (double)T_ * (double)sy2m - (double)sym * (double)sym;
    double contrib = 1.0 - num / sqrt(vx * vy);

#pragma unroll
    for (int off = 32; off; off >>= 1) contrib += __shfl_down(contrib, off);

    __shared__ double s_pos[4], s_neg[4];
    if (lane == 0) {
        double d = contrib * (1.0 / B_);
        double term = exp(d / 0.08);
        double p = 0.0, q = 0.0;
        if (mat == 0) { if (n < m) p = term; }   // strict upper triangle
        else q = term;
        s_pos[w] = p; s_neg[w] = q;
    }
    __syncthreads();
    if (tid == 0) {
        atomicAdd(&accs[0], s_pos[0] + s_pos[1] + s_pos[2] + s_pos[3]);
        atomicAdd(&accs[1], s_neg[0] + s_neg[1] + s_neg[2] + s_neg[3]);
        __threadfence();
        const unsigned old = atomicAdd(ctr, 1u);
        if (old == gridDim.x - 1) {              // last block finalizes
            __threadfence();
            const double p = ((volatile double*)accs)[0];
            const double q = ((volatile double*)accs)[1];
            out[0] = (float)log10(p / q + 1.0);
        }
    }
}

extern "C" void kernel_launch(void* const* d_in, const int* in_sizes, int n_in,
                              void* d_out, int out_size, void* d_ws, size_t ws_size,
                              hipStream_t stream) {
    (void)in_sizes; (void)n_in; (void)out_size; (void)ws_size;
    const float* pos = (const float*)d_in[0];
    const float* neg = (const float*)d_in[1];
    float* out = (float*)d_out;

    char* ws = (char*)d_ws;
    float* partial = (float*)ws;                               // 1024*2176*4 = 8,912,896 B
    float* red = (float*)(ws + (size_t)NBLK1 * PS * 4);        //   64*2176*4 =   557,056 B
    double* accs = (double*)(ws + (size_t)NBLK1 * PS * 4 + (size_t)64 * PS * 4);
    unsigned* ctr = (unsigned*)((char*)accs + 16);

    k_stage1<<<NBLK1, 256, 0, stream>>>(pos, neg, partial, accs, ctr);
    k_reduce<<<dim3(17, 64), 128, 0, stream>>>(partial, red);
    k_entries<<<512, 256, 0, stream>>>(red, accs, ctr, out);
}